// Round 17
// baseline (24.847 us; speedup 1.0000x reference)
//
#include <hip/hip_runtime.h>

// ResonantHTT embedding via two pair tables (b-major, natural u layout):
//   T[p01][b][u], F[p23][b][v];  out[n, u*16+v] = sum_b T[p01][b][u]*F[p23][b][v]
// k_outD: lane = u.
//   T: 16 dense global_load_dword (256B/instr, zero redundancy).
//   F: readfirstlane(p23) -> wave-uniform reads -> scalar K$ path (s_load),
//      FMA consumes the SGPR operand directly. No F vector traffic.
//   Out: transpose via stride-20 padded LDS (8 ops/wave, 16B-aligned)
//      -> 4 contiguous 1KB NT stores (full 64B lines per instruction).

typedef float f32x4 __attribute__((ext_vector_type(4)));

__global__ __launch_bounds__(256) void k_tables(
    const float* __restrict__ core0, const float* __restrict__ core1,
    const float* __restrict__ core2, const float* __restrict__ core3,
    const float* __restrict__ phase,
    float* __restrict__ T, float* __restrict__ F)
{
  const int gid = blockIdx.x * 256 + threadIdx.x;
  const int lane = threadIdx.x & 63;
  const float cown = cosf(phase[lane & 15]);   // cos(phase) per 16-lane seg
  if (blockIdx.x < 1024) {
    // ---- T: 262144 outputs, one per thread, b-major natural-u write ----
    const int p01 = gid >> 10, r = gid & 1023;
    const int b = r >> 6, u = r & 63;
    const int D0 = u >> 3, d1 = u & 7;
    const int i0 = p01 >> 4, i1 = p01 & 15;
    const float* c0 = core0 + i0 * 128 + D0;          // [a] stride 8
    const float* c1 = core1 + i1 * 2048 + b * 8 + d1; // [a] stride 128
    float acc = 0.f;
    #pragma unroll
    for (int a = 0; a < 16; ++a) {
      const float ca = __shfl(cown, a, 16);
      acc += c0[a * 8] * ca * c1[a * 128];
    }
    T[p01 * 1024 + b * 64 + u] = acc;
  } else {
    // ---- F: 65536 outputs, one per thread, coalesced b-major write ----
    const int o = gid - 262144;
    const int p23 = o >> 8, r = o & 255;
    const int b = r >> 4, v = r & 15;
    const int d2 = v >> 2, d3 = v & 3;
    const int i2 = p23 >> 4, i3 = p23 & 15;
    const float* c2 = core2 + i2 * 1024 + b * 64 + d2; // [c] stride 4
    const float* c3 = core3 + i3 * 64 + d3;            // [c] stride 4
    float acc = 0.f;
    #pragma unroll
    for (int c = 0; c < 16; ++c)
      acc += c2[c * 4] * c3[c * 4];
    F[p23 * 256 + b * 16 + v] = acc;
  }
}

__global__ __launch_bounds__(256) void k_outD(
    const int* __restrict__ ids, const float* __restrict__ T,
    const float* __restrict__ F, float* __restrict__ out)
{
  __shared__ float xp[4][64 * 20];              // 5KB/wave transpose buffer
  const int wv = threadIdx.x >> 6, lane = threadIdx.x & 63;
  const int n = blockIdx.x * 4 + wv;            // one token per wave
  const int id = ids[n];
  const int p01 = id >> 8;
  const int p23 = __builtin_amdgcn_readfirstlane(id & 255);  // force SGPR
  const float* __restrict__ Fp = F + p23 * 256; // uniform base -> K$ path

  // ---- T: u = lane; 16 dense 256B dword loads, zero redundancy ----
  float treg[16];
  const float* Tp = T + p01 * 1024 + lane;
  #pragma unroll
  for (int b = 0; b < 16; ++b)
    treg[b] = Tp[b * 64];

  float acc[16];                                // acc[v], u = lane
  #pragma unroll
  for (int v = 0; v < 16; ++v) acc[v] = 0.f;

  #pragma unroll
  for (int b = 0; b < 16; ++b) {
    // wave-uniform F row chunk: scalar loads (SMEM), SGPR FMA operands
    const f32x4 f0 = *reinterpret_cast<const f32x4*>(Fp + b * 16);
    const f32x4 f1 = *reinterpret_cast<const f32x4*>(Fp + b * 16 + 4);
    const f32x4 f2 = *reinterpret_cast<const f32x4*>(Fp + b * 16 + 8);
    const f32x4 f3 = *reinterpret_cast<const f32x4*>(Fp + b * 16 + 12);
    const float tb = treg[b];
    acc[0]  = fmaf(tb, f0.x, acc[0]);  acc[1]  = fmaf(tb, f0.y, acc[1]);
    acc[2]  = fmaf(tb, f0.z, acc[2]);  acc[3]  = fmaf(tb, f0.w, acc[3]);
    acc[4]  = fmaf(tb, f1.x, acc[4]);  acc[5]  = fmaf(tb, f1.y, acc[5]);
    acc[6]  = fmaf(tb, f1.z, acc[6]);  acc[7]  = fmaf(tb, f1.w, acc[7]);
    acc[8]  = fmaf(tb, f2.x, acc[8]);  acc[9]  = fmaf(tb, f2.y, acc[9]);
    acc[10] = fmaf(tb, f2.z, acc[10]); acc[11] = fmaf(tb, f2.w, acc[11]);
    acc[12] = fmaf(tb, f3.x, acc[12]); acc[13] = fmaf(tb, f3.y, acc[13]);
    acc[14] = fmaf(tb, f3.z, acc[14]); acc[15] = fmaf(tb, f3.w, acc[15]);
  }

  // ---- transpose via padded LDS (stride 20 dwords, 16B-aligned) ----
  float* xw = xp[wv];
  #pragma unroll
  for (int e = 0; e < 4; ++e) {
    f32x4 w = { acc[e*4+0], acc[e*4+1], acc[e*4+2], acc[e*4+3] };
    *reinterpret_cast<f32x4*>(xw + lane * 20 + e * 4) = w;
  }
  __syncthreads();   // cross-lane LDS RAW ordering (R7 lesson)

  // store k: lane l -> out[n*1024 + k*256 + l*4 + j]
  //   = element (u = k*16 + (l>>2), v = (l&3)*4 + j) from lane u's row.
  // Each store instr: 64 lanes x 16B CONTIGUOUS = 1KB, full 64B lines.
  float* op = out + (size_t)n * 1024 + lane * 4;
  #pragma unroll
  for (int k = 0; k < 4; ++k) {
    const f32x4 r = *reinterpret_cast<const f32x4*>(
        xw + (k * 16 + (lane >> 2)) * 20 + (lane & 3) * 4);
    __builtin_nontemporal_store(r, reinterpret_cast<f32x4*>(op + k * 256));
  }
}

extern "C" void kernel_launch(void* const* d_in, const int* in_sizes, int n_in,
                              void* d_out, int out_size, void* d_ws, size_t ws_size,
                              hipStream_t stream) {
  const int*   ids   = (const int*)  d_in[0];
  const float* core0 = (const float*)d_in[1];
  const float* core1 = (const float*)d_in[2];
  const float* core2 = (const float*)d_in[3];
  const float* core3 = (const float*)d_in[4];
  const float* phase = (const float*)d_in[5];
  float* out = (float*)d_out;

  float* Tt = (float*)d_ws;                    // 1 MB
  float* Ft = (float*)d_ws + 262144;           // 256 KB

  const int tokens = in_sizes[0];              // 16384
  hipLaunchKernelGGL(k_tables, dim3(1280), dim3(256), 0, stream,
                     core0, core1, core2, core3, phase, Tt, Ft);
  hipLaunchKernelGGL(k_outD, dim3(tokens / 4), dim3(256), 0, stream,
                     ids, Tt, Ft, out);
}

// Round 18
// 24.444 us; speedup vs baseline: 1.0165x; 1.0165x over previous
//
#include <hip/hip_runtime.h>

// ResonantHTT embedding via two pair tables (b-major layout, u-permuted T):
//   T[p01][b][us] (us = (u>>4) + (u&15)*4), F[p23][b][v]
//   out[n, u*16+v] = sum_b T[p01][b][us(u)] * F[p23][b][v]
// k_outE: PERSISTENT waves (fill-kernel style). 1024 blocks x 4 waves =
// 4096 waves; wave w handles tokens {it*4096 + w, it=0..3}. Iteration it's
// grid-wide stores cover ONE contiguous 16MB window sweeping forward
// (DRAM-row-friendly sliding front, store queues continuously fed).
// Per token: T in regs (16 coalesced f32x4), F via double-buffered LDS
// (1 coalesced 1KB load), 4 contiguous 1KB NT stores. 1 barrier/iter.

typedef float f32x4 __attribute__((ext_vector_type(4)));

__global__ __launch_bounds__(256) void k_tables(
    const float* __restrict__ core0, const float* __restrict__ core1,
    const float* __restrict__ core2, const float* __restrict__ core3,
    const float* __restrict__ phase,
    float* __restrict__ T, float* __restrict__ F)
{
  const int gid = blockIdx.x * 256 + threadIdx.x;
  const int lane = threadIdx.x & 63;
  const float cown = cosf(phase[lane & 15]);   // cos(phase) per 16-lane seg
  if (blockIdx.x < 1024) {
    // ---- T: 262144 outputs, one per thread, b-major + u-permuted write ----
    const int p01 = gid >> 10, r = gid & 1023;
    const int b = r >> 6, u = r & 63;
    const int D0 = u >> 3, d1 = u & 7;
    const int i0 = p01 >> 4, i1 = p01 & 15;
    const float* c0 = core0 + i0 * 128 + D0;          // [a] stride 8
    const float* c1 = core1 + i1 * 2048 + b * 8 + d1; // [a] stride 128
    float acc = 0.f;
    #pragma unroll
    for (int a = 0; a < 16; ++a) {
      const float ca = __shfl(cown, a, 16);
      acc += c0[a * 8] * ca * c1[a * 128];
    }
    const int us = (u >> 4) + (u & 15) * 4;           // store-permutation
    T[p01 * 1024 + b * 64 + us] = acc;
  } else {
    // ---- F: 65536 outputs, one per thread, coalesced b-major write ----
    const int o = gid - 262144;
    const int p23 = o >> 8, r = o & 255;
    const int b = r >> 4, v = r & 15;
    const int d2 = v >> 2, d3 = v & 3;
    const int i2 = p23 >> 4, i3 = p23 & 15;
    const float* c2 = core2 + i2 * 1024 + b * 64 + d2; // [c] stride 4
    const float* c3 = core3 + i3 * 64 + d3;            // [c] stride 4
    float acc = 0.f;
    #pragma unroll
    for (int c = 0; c < 16; ++c)
      acc += c2[c * 4] * c3[c * 4];
    F[p23 * 256 + b * 16 + v] = acc;
  }
}

__global__ __launch_bounds__(256) void k_outE(
    const int* __restrict__ ids, const float* __restrict__ T,
    const float* __restrict__ F, float* __restrict__ out, int nwaves)
{
  __shared__ float sF[4][2][256];               // per wave, double-buffered
  const int wv = threadIdx.x >> 6, lane = threadIdx.x & 63;
  const int w = blockIdx.x * 4 + wv;            // persistent wave id
  const int ug = lane >> 2, vg = lane & 3;

  // ---- prologue: stage iteration 0 ----
  int id = ids[w];
  int p01 = id >> 8, p23 = id & 255;
  {
    const f32x4 v = *reinterpret_cast<const f32x4*>(F + p23 * 256 + lane * 4);
    *reinterpret_cast<f32x4*>(&sF[wv][0][lane * 4]) = v;
  }
  f32x4 treg[16];
  {
    const float* Tp = T + p01 * 1024 + ug * 4;
    #pragma unroll
    for (int b = 0; b < 16; ++b)
      treg[b] = *reinterpret_cast<const f32x4*>(Tp + b * 64);
  }

  #pragma unroll
  for (int it = 0; it < 4; ++it) {
    __syncthreads();           // orders buf[it&1] stage-writes before reads
    const float* tF = &sF[wv][it & 1][0];

    // prefetch next iteration: F-stage into other buffer (overlaps compute)
    int nid = 0;
    if (it < 3) {
      nid = ids[w + (it + 1) * 4096];
      const f32x4 v = *reinterpret_cast<const f32x4*>(
          F + (nid & 255) * 256 + lane * 4);
      *reinterpret_cast<f32x4*>(&sF[wv][(it + 1) & 1][lane * 4]) = v;
    }

    float acc[4][4];           // acc[e][j]: u = e*16+ug, v = vg*4+j
    #pragma unroll
    for (int i = 0; i < 4; ++i)
      #pragma unroll
      for (int j = 0; j < 4; ++j) acc[i][j] = 0.f;

    #pragma unroll
    for (int b = 0; b < 16; ++b) {
      const f32x4 f = *reinterpret_cast<const f32x4*>(tF + b * 16 + vg * 4);
      const f32x4 t = treg[b];
      acc[0][0] += t.x*f.x; acc[0][1] += t.x*f.y; acc[0][2] += t.x*f.z; acc[0][3] += t.x*f.w;
      acc[1][0] += t.y*f.x; acc[1][1] += t.y*f.y; acc[1][2] += t.y*f.z; acc[1][3] += t.y*f.w;
      acc[2][0] += t.z*f.x; acc[2][1] += t.z*f.y; acc[2][2] += t.z*f.z; acc[2][3] += t.z*f.w;
      acc[3][0] += t.w*f.x; acc[3][1] += t.w*f.y; acc[3][2] += t.w*f.z; acc[3][3] += t.w*f.w;
    }

    // 4 contiguous 1KB NT stores into the sliding window
    float* op = out + (size_t)(it * 4096 + w) * 1024 + lane * 4;
    #pragma unroll
    for (int e = 0; e < 4; ++e) {
      f32x4 v4 = { acc[e][0], acc[e][1], acc[e][2], acc[e][3] };
      __builtin_nontemporal_store(v4, reinterpret_cast<f32x4*>(op + e * 256));
    }

    // T loads for next iteration (treg now free)
    if (it < 3) {
      const float* Tp = T + (nid >> 8) * 1024 + ug * 4;
      #pragma unroll
      for (int b = 0; b < 16; ++b)
        treg[b] = *reinterpret_cast<const f32x4*>(Tp + b * 64);
    }
  }
}

extern "C" void kernel_launch(void* const* d_in, const int* in_sizes, int n_in,
                              void* d_out, int out_size, void* d_ws, size_t ws_size,
                              hipStream_t stream) {
  const int*   ids   = (const int*)  d_in[0];
  const float* core0 = (const float*)d_in[1];
  const float* core1 = (const float*)d_in[2];
  const float* core2 = (const float*)d_in[3];
  const float* core3 = (const float*)d_in[4];
  const float* phase = (const float*)d_in[5];
  float* out = (float*)d_out;

  float* Tt = (float*)d_ws;                    // 1 MB
  float* Ft = (float*)d_ws + 262144;           // 256 KB

  const int tokens = in_sizes[0];              // 16384
  hipLaunchKernelGGL(k_tables, dim3(1280), dim3(256), 0, stream,
                     core0, core1, core2, core3, phase, Tt, Ft);
  hipLaunchKernelGGL(k_outE, dim3(1024), dim3(256), 0, stream,
                     ids, Tt, Ft, out, tokens / 4);
}